// Round 4
// baseline (337.595 us; speedup 1.0000x reference)
//
#include <hip/hip_runtime.h>
#include <hip/hip_bf16.h>
#include <math.h>

// Problem constants (B=1)
#define SEQ    4096
#define DMODEL 1024
#define NHEADS 8
#define DH     64
#define DINNER 512      // NHEADS*DH
#define NQKV   1536     // 3*DINNER
#define WINDOW 128
#define PERSIST 4
#define EPS 1.1920929e-07f

typedef unsigned short u16;
typedef unsigned int   u32;
typedef __bf16  bf16_8 __attribute__((ext_vector_type(8)));
typedef float   f32x4  __attribute__((ext_vector_type(4)));

union BV { bf16_8 v; u16 s[8]; };

__device__ __forceinline__ float b2f(u16 u) {
    union { u32 i; float f; } v; v.i = ((u32)u) << 16; return v.f;
}
__device__ __forceinline__ u16 f2b(float f) {
    union { float f; u32 i; } v; v.f = f;
    u32 i = v.i;
    u32 r = (i + 0x7fffu + ((i >> 16) & 1u)) >> 16;   // round-to-nearest-even
    return (u16)r;
}

// ---------------- fp32 -> bf16 weight conversion ----------------
__global__ __launch_bounds__(256) void convert_kernel(const float* __restrict__ wqkv,
                                                      const float* __restrict__ wout,
                                                      u16* __restrict__ wqkv_b,
                                                      u16* __restrict__ wout_b) {
    int idx = blockIdx.x * 256 + threadIdx.x;         // 0 .. 524287 (float4 groups)
    const int QKV_GROUPS = (DMODEL * NQKV) / 4;       // 393216
    const float* src;
    u16* dst;
    int off;
    if (idx < QKV_GROUPS) { src = wqkv; dst = wqkv_b; off = idx * 4; }
    else                  { src = wout; dst = wout_b; off = (idx - QKV_GROUPS) * 4; }
    float4 v = *(const float4*)(src + off);
    uint2 o;
    o.x = (u32)f2b(v.x) | ((u32)f2b(v.y) << 16);
    o.y = (u32)f2b(v.z) | ((u32)f2b(v.w) << 16);
    *(uint2*)(dst + off) = o;
}

// ---------------- RMSNorm (fp32 in, bf16 out) ----------------
__global__ __launch_bounds__(256) void rmsnorm_kernel(const float* __restrict__ seq,
                                                      const float* __restrict__ g,
                                                      u16* __restrict__ x) {
    int row = blockIdx.x, tid = threadIdx.x;          // 256 threads, 4 elems each
    float4 v = *(const float4*)(seq + (size_t)row * DMODEL + tid * 4);
    float ss = v.x*v.x + v.y*v.y + v.z*v.z + v.w*v.w;
    #pragma unroll
    for (int o = 32; o > 0; o >>= 1) ss += __shfl_xor(ss, o);
    __shared__ float wsum[4];
    if ((tid & 63) == 0) wsum[tid >> 6] = ss;
    __syncthreads();
    float tot = wsum[0] + wsum[1] + wsum[2] + wsum[3];
    float rstd = rsqrtf(tot * (1.0f / DMODEL) + EPS);
    float4 gv = *(const float4*)(g + tid * 4);
    uint2 o;
    o.x = (u32)f2b(v.x * rstd * gv.x) | ((u32)f2b(v.y * rstd * gv.y) << 16);
    o.y = (u32)f2b(v.z * rstd * gv.z) | ((u32)f2b(v.w * rstd * gv.w) << 16);
    *(uint2*)(x + (size_t)row * DMODEL + tid * 4) = o;
}

// ---------------- bf16 MFMA GEMM: C[M,N] = A[M,K] @ B[K,N] ----------------
// 64x64 tile per 256-thread block.
// MODE 0: scatter bf16 C (N=1536) into q/k/v [head][n][64].
// MODE 1: row-major FP32 write to Cf.
#define BM 64
#define BN 64
#define BK 32
#define LDAS 40
#define LDBS 40

template <int MODE>
__global__ __launch_bounds__(256) void gemm_kernel(const u16* __restrict__ A,
                                                   const u16* __restrict__ B,
                                                   u16* __restrict__ C0,
                                                   u16* __restrict__ C1,
                                                   u16* __restrict__ C2,
                                                   float* __restrict__ Cf,
                                                   int M, int N, int K) {
    __shared__ u16 As[BM * LDAS];
    __shared__ u16 Bs[BN * LDBS];   // transposed: Bs[n][k]
    int bx = blockIdx.x, by = blockIdx.y, tid = threadIdx.x;
    int lane = tid & 63, wave = tid >> 6;
    int quad = lane >> 4, mrow = lane & 15;

    f32x4 acc[4];
    #pragma unroll
    for (int j = 0; j < 4; j++) acc[j] = (f32x4){0.f, 0.f, 0.f, 0.f};

    int arow = tid >> 2, achk = (tid & 3) * 8;       // A stage: 64 rows x 4 chunks of 8
    int bk = tid >> 3,  bn = (tid & 7) * 8;          // B stage: 32 k x 8 n-chunks of 8
    const u16* Ag = A + (size_t)(by * BM + arow) * K + achk;
    const u16* Bg = B + (size_t)bk * N + bx * BN + bn;

    const u16* a_rd  = As + (wave * 16 + mrow) * LDAS + quad * 8;
    const u16* b_rd0 = Bs + mrow * LDBS + quad * 8;

    for (int k0 = 0; k0 < K; k0 += BK) {
        *(bf16_8*)(As + arow * LDAS + achk) = *(const bf16_8*)(Ag + k0);
        union BV bu; bu.v = *(const bf16_8*)(Bg + (size_t)k0 * N);
        #pragma unroll
        for (int j = 0; j < 8; j++) Bs[(bn + j) * LDBS + bk] = bu.s[j];
        __syncthreads();

        bf16_8 af = *(const bf16_8*)a_rd;
        #pragma unroll
        for (int j = 0; j < 4; j++) {
            bf16_8 bf = *(const bf16_8*)(b_rd0 + j * 16 * LDBS);
            acc[j] = __builtin_amdgcn_mfma_f32_16x16x32_bf16(af, bf, acc[j], 0, 0, 0);
        }
        __syncthreads();
    }

    int row0 = by * BM + wave * 16;
    int col0 = bx * BN;
    #pragma unroll
    for (int j = 0; j < 4; j++) {
        #pragma unroll
        for (int r = 0; r < 4; r++) {
            int row = row0 + quad * 4 + r;           // C/D: row = quad*4 + reg
            int col = col0 + j * 16 + mrow;          //      col = lane&15
            if (MODE == 0) {
                int tens = col >> 9, hh = (col >> 6) & 7, dh = col & 63;
                u16* dst = (tens == 0) ? C0 : ((tens == 1) ? C1 : C2);
                dst[((size_t)hh * SEQ + row) * DH + dh] = f2b(acc[j][r]);
            } else {
                Cf[(size_t)row * N + col] = acc[j][r];   // FP32 output
            }
        }
    }
}

// ---------------- RoPE (interleaved pairs), in place on q and k ----------------
__global__ __launch_bounds__(256) void rope_kernel(u16* __restrict__ Q, u16* __restrict__ Kt) {
    int idx = blockIdx.x * 256 + threadIdx.x;        // 2 * 2^20 threads
    int tensor = idx >> 20;
    int r = idx & 0xfffff;
    int t = r & 31;                                   // pair index 0..31
    int n = (r >> 5) & 4095;
    int h = r >> 17;
    u16* p = (tensor == 0 ? Q : Kt) + ((size_t)h * SEQ + n) * DH + 2 * t;
    float e = (float)(2 * t) / 64.0f;
    float inv = exp2f(-e * 13.287712379549449f);      // 10000^-e
    float ang = (float)n * inv;
    float s, c;
    sincosf(ang, &s, &c);
    float x0 = b2f(p[0]), x1 = b2f(p[1]);
    p[0] = f2b(x0 * c - x1 * s);
    p[1] = f2b(x1 * c + x0 * s);
}

// ---------------- Attention: one wave per (query i, head h) ----------------
__global__ __launch_bounds__(64) void attn_kernel(const u16* __restrict__ Q,
                                                  const u16* __restrict__ Kt,
                                                  const u16* __restrict__ V,
                                                  u16* __restrict__ O) {
    int i = blockIdx.x, h = blockIdx.y, lane = threadIdx.x;
    __shared__ float qs[DH];
    __shared__ float sc[160];
    qs[lane] = b2f(Q[((size_t)h * SEQ + i) * DH + lane]);
    __syncthreads();

    int start = (i > WINDOW) ? (i - WINDOW) : 0;
    int count_p = (start < PERSIST) ? start : PERSIST;
    int total = count_p + (i - start + 1);
    const float scale = 0.125f;                       // 64^-0.5

    for (int t = lane; t < total; t += 64) {
        int j = (t < count_p) ? t : (start + (t - count_p));
        const u16* kp = Kt + ((size_t)h * SEQ + j) * DH;
        float s = 0.f;
        #pragma unroll
        for (int dd = 0; dd < 8; dd++) {
            union BV u; u.v = *(const bf16_8*)(kp + dd * 8);
            #pragma unroll
            for (int e = 0; e < 8; e++) s += qs[dd * 8 + e] * b2f(u.s[e]);
        }
        sc[t] = s * scale;
    }
    __syncthreads();

    float m = -1e30f;
    for (int t = lane; t < total; t += 64) m = fmaxf(m, sc[t]);
    #pragma unroll
    for (int o = 32; o > 0; o >>= 1) m = fmaxf(m, __shfl_xor(m, o));

    float sum = 0.f;
    for (int t = lane; t < total; t += 64) { float e = expf(sc[t] - m); sc[t] = e; sum += e; }
    #pragma unroll
    for (int o = 32; o > 0; o >>= 1) sum += __shfl_xor(sum, o);
    __syncthreads();

    float oacc = 0.f;
    int d = lane;
    for (int t = 0; t < total; t++) {
        int j = (t < count_p) ? t : (start + (t - count_p));
        oacc += sc[t] * b2f(V[((size_t)h * SEQ + j) * DH + d]);
    }
    O[(size_t)i * DINNER + h * DH + d] = f2b(oacc / sum);
}

// ---------------- launch ----------------
extern "C" void kernel_launch(void* const* d_in, const int* in_sizes, int n_in,
                              void* d_out, int out_size, void* d_ws, size_t ws_size,
                              hipStream_t stream) {
    const float* seq  = (const float*)d_in[0];   // fp32 inputs
    const float* g    = (const float*)d_in[1];
    const float* wqkv = (const float*)d_in[2];
    const float* wout = (const float*)d_in[3];
    float* out = (float*)d_out;                   // FP32 output (reference output dtype)

    char* ws = (char*)d_ws;
    u16* x      = (u16*)(ws);                             // 8 MB
    u16* q      = (u16*)(ws + 8ll  * 1024 * 1024);        // 4 MB
    u16* k      = (u16*)(ws + 12ll * 1024 * 1024);        // 4 MB
    u16* v      = (u16*)(ws + 16ll * 1024 * 1024);        // 4 MB
    u16* att    = (u16*)(ws + 20ll * 1024 * 1024);        // 4 MB
    u16* wqkv_b = (u16*)(ws + 24ll * 1024 * 1024);        // 3 MB
    u16* wout_b = (u16*)(ws + 27ll * 1024 * 1024);        // 1 MB

    convert_kernel<<<2048, 256, 0, stream>>>(wqkv, wout, wqkv_b, wout_b);

    rmsnorm_kernel<<<SEQ, 256, 0, stream>>>(seq, g, x);

    dim3 g1(NQKV / BN, SEQ / BM);
    gemm_kernel<0><<<g1, 256, 0, stream>>>(x, wqkv_b, q, k, v, nullptr, SEQ, NQKV, DMODEL);

    rope_kernel<<<(2 * 1048576) / 256, 256, 0, stream>>>(q, k);

    dim3 g2(SEQ, NHEADS);
    attn_kernel<<<g2, 64, 0, stream>>>(q, k, v, att);

    dim3 g3(DMODEL / BN, SEQ / BM);
    gemm_kernel<1><<<g3, 256, 0, stream>>>(att, wout_b, nullptr, nullptr, nullptr, out, SEQ, DMODEL, DINNER);
}

// Round 5
// 259.502 us; speedup vs baseline: 1.3009x; 1.3009x over previous
//
#include <hip/hip_runtime.h>
#include <hip/hip_bf16.h>
#include <math.h>

// Problem constants (B=1)
#define SEQ    4096
#define DMODEL 1024
#define NHEADS 8
#define DH     64
#define DINNER 512      // NHEADS*DH
#define NQKV   1536     // 3*DINNER
#define WINDOW 128
#define PERSIST 4
#define EPS 1.1920929e-07f

typedef unsigned short u16;
typedef unsigned int   u32;
typedef __bf16  bf16_8 __attribute__((ext_vector_type(8)));
typedef float   f32x4  __attribute__((ext_vector_type(4)));

union BV { bf16_8 v; u16 s[8]; };

__device__ __forceinline__ float b2f(u16 u) {
    union { u32 i; float f; } v; v.i = ((u32)u) << 16; return v.f;
}
__device__ __forceinline__ u16 f2b(float f) {
    union { float f; u32 i; } v; v.f = f;
    u32 i = v.i;
    u32 r = (i + 0x7fffu + ((i >> 16) & 1u)) >> 16;   // round-to-nearest-even
    return (u16)r;
}

// ---------------- fp32 -> bf16 weight conversion ----------------
__global__ __launch_bounds__(256) void convert_kernel(const float* __restrict__ wqkv,
                                                      const float* __restrict__ wout,
                                                      u16* __restrict__ wqkv_b,
                                                      u16* __restrict__ wout_b) {
    int idx = blockIdx.x * 256 + threadIdx.x;         // 0 .. 524287 (float4 groups)
    const int QKV_GROUPS = (DMODEL * NQKV) / 4;       // 393216
    const float* src;
    u16* dst;
    int off;
    if (idx < QKV_GROUPS) { src = wqkv; dst = wqkv_b; off = idx * 4; }
    else                  { src = wout; dst = wout_b; off = (idx - QKV_GROUPS) * 4; }
    float4 v = *(const float4*)(src + off);
    uint2 o;
    o.x = (u32)f2b(v.x) | ((u32)f2b(v.y) << 16);
    o.y = (u32)f2b(v.z) | ((u32)f2b(v.w) << 16);
    *(uint2*)(dst + off) = o;
}

// ---------------- RMSNorm (fp32 in, bf16 out) ----------------
__global__ __launch_bounds__(256) void rmsnorm_kernel(const float* __restrict__ seq,
                                                      const float* __restrict__ g,
                                                      u16* __restrict__ x) {
    int row = blockIdx.x, tid = threadIdx.x;          // 256 threads, 4 elems each
    float4 v = *(const float4*)(seq + (size_t)row * DMODEL + tid * 4);
    float ss = v.x*v.x + v.y*v.y + v.z*v.z + v.w*v.w;
    #pragma unroll
    for (int o = 32; o > 0; o >>= 1) ss += __shfl_xor(ss, o);
    __shared__ float wsum[4];
    if ((tid & 63) == 0) wsum[tid >> 6] = ss;
    __syncthreads();
    float tot = wsum[0] + wsum[1] + wsum[2] + wsum[3];
    float rstd = rsqrtf(tot * (1.0f / DMODEL) + EPS);
    float4 gv = *(const float4*)(g + tid * 4);
    uint2 o;
    o.x = (u32)f2b(v.x * rstd * gv.x) | ((u32)f2b(v.y * rstd * gv.y) << 16);
    o.y = (u32)f2b(v.z * rstd * gv.z) | ((u32)f2b(v.w * rstd * gv.w) << 16);
    *(uint2*)(x + (size_t)row * DMODEL + tid * 4) = o;
}

// ---------------- bf16 MFMA GEMM: C[M,N] = A[M,K] @ B[K,N] ----------------
// 64x64 tile per 256-thread block.
// MODE 0: scatter bf16 C (N=1536) into q/k/v [head][n][64].
// MODE 1: row-major FP32 write to Cf.
#define BM 64
#define BN 64
#define BK 32
#define LDAS 40
#define LDBS 40

template <int MODE>
__global__ __launch_bounds__(256) void gemm_kernel(const u16* __restrict__ A,
                                                   const u16* __restrict__ B,
                                                   u16* __restrict__ C0,
                                                   u16* __restrict__ C1,
                                                   u16* __restrict__ C2,
                                                   float* __restrict__ Cf,
                                                   int M, int N, int K) {
    __shared__ u16 As[BM * LDAS];
    __shared__ u16 Bs[BN * LDBS];   // transposed: Bs[n][k]
    int bx = blockIdx.x, by = blockIdx.y, tid = threadIdx.x;
    int lane = tid & 63, wave = tid >> 6;
    int quad = lane >> 4, mrow = lane & 15;

    f32x4 acc[4];
    #pragma unroll
    for (int j = 0; j < 4; j++) acc[j] = (f32x4){0.f, 0.f, 0.f, 0.f};

    int arow = tid >> 2, achk = (tid & 3) * 8;       // A stage: 64 rows x 4 chunks of 8
    int bk = tid >> 3,  bn = (tid & 7) * 8;          // B stage: 32 k x 8 n-chunks of 8
    const u16* Ag = A + (size_t)(by * BM + arow) * K + achk;
    const u16* Bg = B + (size_t)bk * N + bx * BN + bn;

    const u16* a_rd  = As + (wave * 16 + mrow) * LDAS + quad * 8;
    const u16* b_rd0 = Bs + mrow * LDBS + quad * 8;

    for (int k0 = 0; k0 < K; k0 += BK) {
        *(bf16_8*)(As + arow * LDAS + achk) = *(const bf16_8*)(Ag + k0);
        union BV bu; bu.v = *(const bf16_8*)(Bg + (size_t)k0 * N);
        #pragma unroll
        for (int j = 0; j < 8; j++) Bs[(bn + j) * LDBS + bk] = bu.s[j];
        __syncthreads();

        bf16_8 af = *(const bf16_8*)a_rd;
        #pragma unroll
        for (int j = 0; j < 4; j++) {
            bf16_8 bf = *(const bf16_8*)(b_rd0 + j * 16 * LDBS);
            acc[j] = __builtin_amdgcn_mfma_f32_16x16x32_bf16(af, bf, acc[j], 0, 0, 0);
        }
        __syncthreads();
    }

    int row0 = by * BM + wave * 16;
    int col0 = bx * BN;
    #pragma unroll
    for (int j = 0; j < 4; j++) {
        #pragma unroll
        for (int r = 0; r < 4; r++) {
            int row = row0 + quad * 4 + r;           // C/D: row = quad*4 + reg
            int col = col0 + j * 16 + mrow;          //      col = lane&15
            if (MODE == 0) {
                int tens = col >> 9, hh = (col >> 6) & 7, dh = col & 63;
                u16* dst = (tens == 0) ? C0 : ((tens == 1) ? C1 : C2);
                dst[((size_t)hh * SEQ + row) * DH + dh] = f2b(acc[j][r]);
            } else {
                Cf[(size_t)row * N + col] = acc[j][r];   // FP32 output
            }
        }
    }
}

// ---------------- RoPE (interleaved pairs), in place on q and k ----------------
__global__ __launch_bounds__(256) void rope_kernel(u16* __restrict__ Q, u16* __restrict__ Kt) {
    int idx = blockIdx.x * 256 + threadIdx.x;        // 2 * 2^20 threads
    int tensor = idx >> 20;
    int r = idx & 0xfffff;
    int t = r & 31;                                   // pair index 0..31
    int n = (r >> 5) & 4095;
    int h = r >> 17;
    u16* p = (tensor == 0 ? Q : Kt) + ((size_t)h * SEQ + n) * DH + 2 * t;
    float e = (float)(2 * t) / 64.0f;
    float inv = exp2f(-e * 13.287712379549449f);      // 10000^-e
    float ang = (float)n * inv;
    float s, c;
    sincosf(ang, &s, &c);
    float x0 = b2f(p[0]), x1 = b2f(p[1]);
    p[0] = f2b(x0 * c - x1 * s);
    p[1] = f2b(x1 * c + x0 * s);
}

// ---------------- Attention v2: LDS-staged K/V, 4 queries (4 waves) per block ----------------
// Block handles queries i0..i0+3 of head h. LDS rows 0..131 = window keys
// [smin .. i0+3] (smin = max(0, i0-128)); rows 132..135 = persist keys 0..3.
#define ATT_LD 72     // row stride in elems (144 B, 16B-aligned, breaks pow2 banks)

__global__ __launch_bounds__(256) void attn_kernel2(const u16* __restrict__ Q,
                                                    const u16* __restrict__ Kt,
                                                    const u16* __restrict__ V,
                                                    u16* __restrict__ O) {
    __shared__ u16 Ks[136 * ATT_LD];
    __shared__ u16 Vs[136 * ATT_LD];
    __shared__ float qs[4 * 64];
    __shared__ float sc[4 * 160];
    int i0 = blockIdx.x * 4, h = blockIdx.y;
    int tid = threadIdx.x, wave = tid >> 6, lane = tid & 63;
    int smin = (i0 > WINDOW) ? i0 - WINDOW : 0;

    // cooperative stage: 136 rows x 8 chunks, K and V together (addresses in-bounds for all rows)
    for (int idx = tid; idx < 136 * 8; idx += 256) {
        int row = idx >> 3, c = (idx & 7) * 8;
        int j = (row < 132) ? (smin + row) : (row - 132);
        size_t goff = ((size_t)h * SEQ + j) * DH + c;
        *(bf16_8*)(Ks + row * ATT_LD + c) = *(const bf16_8*)(Kt + goff);
        *(bf16_8*)(Vs + row * ATT_LD + c) = *(const bf16_8*)(V + goff);
    }
    int i = i0 + wave;
    qs[wave * 64 + lane] = b2f(Q[((size_t)h * SEQ + i) * DH + lane]);
    __syncthreads();

    int start = (i > WINDOW) ? (i - WINDOW) : 0;
    int cp = (start < PERSIST) ? start : PERSIST;
    int total = cp + (i - start) + 1;                 // <= 133
    const float* qw = qs + wave * 64;
    float* scw = sc + wave * 160;

    // QK^T out of LDS
    for (int t = lane; t < total; t += 64) {
        int row = (t < cp) ? (132 + t) : (start - smin + t - cp);
        const u16* kp = Ks + row * ATT_LD;
        float s = 0.f;
        #pragma unroll
        for (int dd = 0; dd < 8; dd++) {
            union BV u; u.v = *(const bf16_8*)(kp + dd * 8);
            #pragma unroll
            for (int e = 0; e < 8; e++) s += qw[dd * 8 + e] * b2f(u.s[e]);
        }
        scw[t] = s * 0.125f;                          // 64^-0.5
    }
    // per-wave softmax (lockstep wave: LDS within wave needs no barrier)
    float m = -1e30f;
    for (int t = lane; t < total; t += 64) m = fmaxf(m, scw[t]);
    #pragma unroll
    for (int o = 32; o > 0; o >>= 1) m = fmaxf(m, __shfl_xor(m, o));
    float sum = 0.f;
    for (int t = lane; t < total; t += 64) { float e = expf(scw[t] - m); scw[t] = e; sum += e; }
    #pragma unroll
    for (int o = 32; o > 0; o >>= 1) sum += __shfl_xor(sum, o);

    // PV out of LDS: lane = output dim
    float oacc = 0.f;
    int d = lane;
    for (int t = 0; t < total; t++) {
        int row = (t < cp) ? (132 + t) : (start - smin + t - cp);
        oacc += scw[t] * b2f(Vs[row * ATT_LD + d]);
    }
    O[(size_t)i * DINNER + h * DH + d] = f2b(oacc / sum);
}

// ---------------- launch ----------------
extern "C" void kernel_launch(void* const* d_in, const int* in_sizes, int n_in,
                              void* d_out, int out_size, void* d_ws, size_t ws_size,
                              hipStream_t stream) {
    const float* seq  = (const float*)d_in[0];   // fp32 inputs
    const float* g    = (const float*)d_in[1];
    const float* wqkv = (const float*)d_in[2];
    const float* wout = (const float*)d_in[3];
    float* out = (float*)d_out;                   // fp32 output

    char* ws = (char*)d_ws;
    u16* x      = (u16*)(ws);                             // 8 MB
    u16* q      = (u16*)(ws + 8ll  * 1024 * 1024);        // 4 MB
    u16* k      = (u16*)(ws + 12ll * 1024 * 1024);        // 4 MB
    u16* v      = (u16*)(ws + 16ll * 1024 * 1024);        // 4 MB
    u16* att    = (u16*)(ws + 20ll * 1024 * 1024);        // 4 MB
    u16* wqkv_b = (u16*)(ws + 24ll * 1024 * 1024);        // 3 MB
    u16* wout_b = (u16*)(ws + 27ll * 1024 * 1024);        // 1 MB

    convert_kernel<<<2048, 256, 0, stream>>>(wqkv, wout, wqkv_b, wout_b);

    rmsnorm_kernel<<<SEQ, 256, 0, stream>>>(seq, g, x);

    dim3 g1(NQKV / BN, SEQ / BM);
    gemm_kernel<0><<<g1, 256, 0, stream>>>(x, wqkv_b, q, k, v, nullptr, SEQ, NQKV, DMODEL);

    rope_kernel<<<(2 * 1048576) / 256, 256, 0, stream>>>(q, k);

    dim3 g2(SEQ / 4, NHEADS);
    attn_kernel2<<<g2, 256, 0, stream>>>(q, k, v, att);

    dim3 g3(DMODEL / BN, SEQ / BM);
    gemm_kernel<1><<<g3, 256, 0, stream>>>(att, wout_b, nullptr, nullptr, nullptr, out, SEQ, DMODEL, DINNER);
}

// Round 6
// 194.750 us; speedup vs baseline: 1.7335x; 1.3325x over previous
//
#include <hip/hip_runtime.h>
#include <hip/hip_bf16.h>
#include <math.h>

// Problem constants (B=1)
#define SEQ    4096
#define DMODEL 1024
#define NHEADS 8
#define DH     64
#define DINNER 512      // NHEADS*DH
#define NQKV   1536     // 3*DINNER
#define WINDOW 128
#define PERSIST 4
#define EPS 1.1920929e-07f

typedef unsigned short u16;
typedef unsigned int   u32;
typedef __bf16  bf16_8 __attribute__((ext_vector_type(8)));
typedef float   f32x4  __attribute__((ext_vector_type(4)));

union BV { bf16_8 v; u16 s[8]; };

__device__ __forceinline__ float b2f(u16 u) {
    union { u32 i; float f; } v; v.i = ((u32)u) << 16; return v.f;
}
__device__ __forceinline__ u16 f2b(float f) {
    union { float f; u32 i; } v; v.f = f;
    u32 i = v.i;
    u32 r = (i + 0x7fffu + ((i >> 16) & 1u)) >> 16;   // round-to-nearest-even
    return (u16)r;
}

// ---------------- fp32 -> bf16 weight conversion ----------------
__global__ __launch_bounds__(256) void convert_kernel(const float* __restrict__ wqkv,
                                                      const float* __restrict__ wout,
                                                      u16* __restrict__ wqkv_b,
                                                      u16* __restrict__ wout_b) {
    int idx = blockIdx.x * 256 + threadIdx.x;         // 0 .. 524287 (float4 groups)
    const int QKV_GROUPS = (DMODEL * NQKV) / 4;       // 393216
    const float* src;
    u16* dst;
    int off;
    if (idx < QKV_GROUPS) { src = wqkv; dst = wqkv_b; off = idx * 4; }
    else                  { src = wout; dst = wout_b; off = (idx - QKV_GROUPS) * 4; }
    float4 v = *(const float4*)(src + off);
    uint2 o;
    o.x = (u32)f2b(v.x) | ((u32)f2b(v.y) << 16);
    o.y = (u32)f2b(v.z) | ((u32)f2b(v.w) << 16);
    *(uint2*)(dst + off) = o;
}

// ---------------- RMSNorm (fp32 in, bf16 out) ----------------
__global__ __launch_bounds__(256) void rmsnorm_kernel(const float* __restrict__ seq,
                                                      const float* __restrict__ g,
                                                      u16* __restrict__ x) {
    int row = blockIdx.x, tid = threadIdx.x;          // 256 threads, 4 elems each
    float4 v = *(const float4*)(seq + (size_t)row * DMODEL + tid * 4);
    float ss = v.x*v.x + v.y*v.y + v.z*v.z + v.w*v.w;
    #pragma unroll
    for (int o = 32; o > 0; o >>= 1) ss += __shfl_xor(ss, o);
    __shared__ float wsum[4];
    if ((tid & 63) == 0) wsum[tid >> 6] = ss;
    __syncthreads();
    float tot = wsum[0] + wsum[1] + wsum[2] + wsum[3];
    float rstd = rsqrtf(tot * (1.0f / DMODEL) + EPS);
    float4 gv = *(const float4*)(g + tid * 4);
    uint2 o;
    o.x = (u32)f2b(v.x * rstd * gv.x) | ((u32)f2b(v.y * rstd * gv.y) << 16);
    o.y = (u32)f2b(v.z * rstd * gv.z) | ((u32)f2b(v.w * rstd * gv.w) << 16);
    *(uint2*)(x + (size_t)row * DMODEL + tid * 4) = o;
}

// ---------------- bf16 MFMA GEMM: C[M,N] = A[M,K] @ B[K,N] ----------------
#define BM 64
#define BN 64
#define BK 32
#define LDAS 40
#define LDBS 40

template <int MODE>
__global__ __launch_bounds__(256) void gemm_kernel(const u16* __restrict__ A,
                                                   const u16* __restrict__ B,
                                                   u16* __restrict__ C0,
                                                   u16* __restrict__ C1,
                                                   u16* __restrict__ C2,
                                                   float* __restrict__ Cf,
                                                   int M, int N, int K) {
    __shared__ u16 As[BM * LDAS];
    __shared__ u16 Bs[BN * LDBS];   // transposed: Bs[n][k]
    int bx = blockIdx.x, by = blockIdx.y, tid = threadIdx.x;
    int lane = tid & 63, wave = tid >> 6;
    int quad = lane >> 4, mrow = lane & 15;

    f32x4 acc[4];
    #pragma unroll
    for (int j = 0; j < 4; j++) acc[j] = (f32x4){0.f, 0.f, 0.f, 0.f};

    int arow = tid >> 2, achk = (tid & 3) * 8;
    int bk = tid >> 3,  bn = (tid & 7) * 8;
    const u16* Ag = A + (size_t)(by * BM + arow) * K + achk;
    const u16* Bg = B + (size_t)bk * N + bx * BN + bn;

    const u16* a_rd  = As + (wave * 16 + mrow) * LDAS + quad * 8;
    const u16* b_rd0 = Bs + mrow * LDBS + quad * 8;

    for (int k0 = 0; k0 < K; k0 += BK) {
        *(bf16_8*)(As + arow * LDAS + achk) = *(const bf16_8*)(Ag + k0);
        union BV bu; bu.v = *(const bf16_8*)(Bg + (size_t)k0 * N);
        #pragma unroll
        for (int j = 0; j < 8; j++) Bs[(bn + j) * LDBS + bk] = bu.s[j];
        __syncthreads();

        bf16_8 af = *(const bf16_8*)a_rd;
        #pragma unroll
        for (int j = 0; j < 4; j++) {
            bf16_8 bf = *(const bf16_8*)(b_rd0 + j * 16 * LDBS);
            acc[j] = __builtin_amdgcn_mfma_f32_16x16x32_bf16(af, bf, acc[j], 0, 0, 0);
        }
        __syncthreads();
    }

    int row0 = by * BM + wave * 16;
    int col0 = bx * BN;
    #pragma unroll
    for (int j = 0; j < 4; j++) {
        #pragma unroll
        for (int r = 0; r < 4; r++) {
            int row = row0 + quad * 4 + r;           // C/D: row = quad*4 + reg
            int col = col0 + j * 16 + mrow;          //      col = lane&15
            if (MODE == 0) {
                int tens = col >> 9, hh = (col >> 6) & 7, dh = col & 63;
                u16* dst = (tens == 0) ? C0 : ((tens == 1) ? C1 : C2);
                dst[((size_t)hh * SEQ + row) * DH + dh] = f2b(acc[j][r]);
            } else {
                Cf[(size_t)row * N + col] = acc[j][r];   // FP32 output
            }
        }
    }
}

// ---------------- RoPE (interleaved pairs), in place on q and k ----------------
__global__ __launch_bounds__(256) void rope_kernel(u16* __restrict__ Q, u16* __restrict__ Kt) {
    int idx = blockIdx.x * 256 + threadIdx.x;        // 2 * 2^20 threads
    int tensor = idx >> 20;
    int r = idx & 0xfffff;
    int t = r & 31;                                   // pair index 0..31
    int n = (r >> 5) & 4095;
    int h = r >> 17;
    u16* p = (tensor == 0 ? Q : Kt) + ((size_t)h * SEQ + n) * DH + 2 * t;
    float e = (float)(2 * t) / 64.0f;
    float inv = exp2f(-e * 13.287712379549449f);      // 10000^-e
    float ang = (float)n * inv;
    float s, c;
    sincosf(ang, &s, &c);
    float x0 = b2f(p[0]), x1 = b2f(p[1]);
    p[0] = f2b(x0 * c - x1 * s);
    p[1] = f2b(x1 * c + x0 * s);
}

// ---------------- Attention v3: MFMA flash-style ----------------
// Block: 64 queries (4 waves x 16) of head h. LDS rows 0..15 = keys 0..15
// (covers persist), rows 16..207 = window union [smin..smin+191].
// Wave slot map: t<16 -> key j=t (row t); t>=16 -> j=start_w+t-16 (row t+Dw,
// Dw=start_w-smin). Row-map jump sits at t=16 (8-aligned) so b128 frags stay
// contiguous. QK^T and PV via mfma_f32_16x16x32_bf16; P via LDS round-trip.
#define AROWS 208
#define KLD   72     // Ks row stride (144 B: 16B-aligned, 2-way banks only)
#define PLD   168    // Ps row stride (336 B: 16B-aligned, 2-way banks only)

__global__ __launch_bounds__(256, 2) void attn_mfma(const u16* __restrict__ Q,
                                                    const u16* __restrict__ Kt,
                                                    const u16* __restrict__ V,
                                                    u16* __restrict__ O) {
    __shared__ u16 Ks[AROWS * KLD];
    __shared__ u16 Vs[AROWS * 64];      // XOR-swizzled 8-elem column groups
    __shared__ u16 Ps[4 * 16 * PLD];
    int i0 = blockIdx.x * 64, h = blockIdx.y;
    int tid = threadIdx.x, wave = tid >> 6, lane = tid & 63;
    int m16 = lane & 15, quad = lane >> 4;
    int smin = (i0 > WINDOW) ? i0 - WINDOW : 0;

    // cooperative K/V staging (all rows are real keys -> finite data)
    for (int idx = tid; idx < AROWS * 8; idx += 256) {
        int row = idx >> 3, c = idx & 7;
        int j = (row < 16) ? row : (smin + row - 16);
        size_t goff = ((size_t)h * SEQ + j) * DH + c * 8;
        *(bf16_8*)(Ks + row * KLD + c * 8) = *(const bf16_8*)(Kt + goff);
        int swz = (row ^ (row >> 3)) & 7;
        *(bf16_8*)(Vs + row * 64 + ((c ^ swz) << 3)) = *(const bf16_8*)(V + goff);
    }

    int iw0 = i0 + wave * 16;
    int iq = iw0 + m16;
    const u16* qrow = Q + ((size_t)h * SEQ + iq) * DH;
    bf16_8 qa = *(const bf16_8*)(qrow + quad * 8);        // A-frag: m=lane&15, k=quad*8+j
    bf16_8 qb = *(const bf16_8*)(qrow + 32 + quad * 8);
    __syncthreads();

    int start_w = (iw0 > WINDOW) ? iw0 - WINDOW : 0;
    int Dw = start_w - smin;
    int tlast = 31 + iw0 - start_w;                       // last meaningful slot
    int nch = (tlast >> 4) + 1;                           // <=10 QK chunks
    int nk32 = (tlast >> 5) + 1;                          // <=5 PV K-chunks

    // ---- QK^T ----
    f32x4 S[10];
    #pragma unroll
    for (int c = 0; c < 10; c++) {
        if (c < nch) {
            int t = c * 16 + m16;
            int row = (c == 0) ? t : (t + Dw);
            const u16* kp = Ks + row * KLD;
            bf16_8 kb0 = *(const bf16_8*)(kp + quad * 8); // B-frag: n=lane&15, k=quad*8+j
            bf16_8 kb1 = *(const bf16_8*)(kp + 32 + quad * 8);
            f32x4 s = (f32x4){0.f, 0.f, 0.f, 0.f};
            s = __builtin_amdgcn_mfma_f32_16x16x32_bf16(qa, kb0, s, 0, 0, 0);
            s = __builtin_amdgcn_mfma_f32_16x16x32_bf16(qb, kb1, s, 0, 0, 0);
            S[c] = s;
        }
    }

    // ---- mask + softmax (C layout: row=quad*4+r, col=lane&15) ----
    float mrow[4] = {-1e30f, -1e30f, -1e30f, -1e30f};
    #pragma unroll
    for (int c = 0; c < 10; c++) {
        if (c < nch) {
            int t = c * 16 + m16;
            int j = (c == 0) ? t : (start_w + t - 16);
            #pragma unroll
            for (int r = 0; r < 4; r++) {
                int i = iw0 + quad * 4 + r;
                bool valid = (c == 0) ? (j < PERSIST && j < start_w)
                                      : (j <= i && (i - j <= WINDOW || j < PERSIST));
                float sv = valid ? S[c][r] * 0.125f : -1e30f;
                S[c][r] = sv;
                mrow[r] = fmaxf(mrow[r], sv);
            }
        }
    }
    #pragma unroll
    for (int r = 0; r < 4; r++) {
        #pragma unroll
        for (int o = 1; o < 16; o <<= 1) mrow[r] = fmaxf(mrow[r], __shfl_xor(mrow[r], o));
    }
    float srow[4] = {0.f, 0.f, 0.f, 0.f};
    #pragma unroll
    for (int c = 0; c < 10; c++) {
        if (c < nch) {
            #pragma unroll
            for (int r = 0; r < 4; r++) {
                float p = expf(S[c][r] - mrow[r]);
                S[c][r] = p;
                srow[r] += p;
            }
        }
    }
    #pragma unroll
    for (int r = 0; r < 4; r++) {
        #pragma unroll
        for (int o = 1; o < 16; o <<= 1) srow[r] += __shfl_xor(srow[r], o);
    }

    // ---- P -> LDS (C layout -> A layout round trip); zero-fill unused slots ----
    u16* pw = Ps + wave * 16 * PLD;
    #pragma unroll
    for (int c = 0; c < 10; c++) {
        #pragma unroll
        for (int r = 0; r < 4; r++) {
            u16 val = (c < nch) ? f2b(S[c][r]) : (u16)0;
            pw[(quad * 4 + r) * PLD + c * 16 + m16] = val;
        }
    }
    // same-wave LDS write->read: ordering enforced by lgkmcnt, no barrier needed

    // ---- PV ----
    f32x4 oacc[4];
    #pragma unroll
    for (int nt = 0; nt < 4; nt++) oacc[nt] = (f32x4){0.f, 0.f, 0.f, 0.f};
    #pragma unroll
    for (int c2 = 0; c2 < 5; c2++) {
        if (c2 < nk32) {
            bf16_8 af = *(const bf16_8*)(pw + m16 * PLD + c2 * 32 + quad * 8);
            #pragma unroll
            for (int nt = 0; nt < 4; nt++) {
                union BV bv;
                int d = nt * 16 + m16;
                #pragma unroll
                for (int jj = 0; jj < 8; jj++) {
                    int k = c2 * 32 + quad * 8 + jj;
                    int row = (k < 16) ? k : (k + Dw);
                    int swz = (row ^ (row >> 3)) & 7;
                    bv.s[jj] = Vs[row * 64 + ((((d >> 3) ^ swz) << 3) | (d & 7))];
                }
                oacc[nt] = __builtin_amdgcn_mfma_f32_16x16x32_bf16(af, bv.v, oacc[nt], 0, 0, 0);
            }
        }
    }

    // ---- normalize + write (bf16 att buffer [4096][512]) ----
    #pragma unroll
    for (int nt = 0; nt < 4; nt++) {
        #pragma unroll
        for (int r = 0; r < 4; r++) {
            int i = iw0 + quad * 4 + r;
            O[(size_t)i * DINNER + h * DH + nt * 16 + m16] = f2b(oacc[nt][r] / srow[r]);
        }
    }
}

// ---------------- launch ----------------
extern "C" void kernel_launch(void* const* d_in, const int* in_sizes, int n_in,
                              void* d_out, int out_size, void* d_ws, size_t ws_size,
                              hipStream_t stream) {
    const float* seq  = (const float*)d_in[0];   // fp32 inputs
    const float* g    = (const float*)d_in[1];
    const float* wqkv = (const float*)d_in[2];
    const float* wout = (const float*)d_in[3];
    float* out = (float*)d_out;                   // fp32 output

    char* ws = (char*)d_ws;
    u16* x      = (u16*)(ws);                             // 8 MB
    u16* q      = (u16*)(ws + 8ll  * 1024 * 1024);        // 4 MB
    u16* k      = (u16*)(ws + 12ll * 1024 * 1024);        // 4 MB
    u16* v      = (u16*)(ws + 16ll * 1024 * 1024);        // 4 MB
    u16* att    = (u16*)(ws + 20ll * 1024 * 1024);        // 4 MB
    u16* wqkv_b = (u16*)(ws + 24ll * 1024 * 1024);        // 3 MB
    u16* wout_b = (u16*)(ws + 27ll * 1024 * 1024);        // 1 MB

    convert_kernel<<<2048, 256, 0, stream>>>(wqkv, wout, wqkv_b, wout_b);

    rmsnorm_kernel<<<SEQ, 256, 0, stream>>>(seq, g, x);

    dim3 g1(NQKV / BN, SEQ / BM);
    gemm_kernel<0><<<g1, 256, 0, stream>>>(x, wqkv_b, q, k, v, nullptr, SEQ, NQKV, DMODEL);

    rope_kernel<<<(2 * 1048576) / 256, 256, 0, stream>>>(q, k);

    dim3 g2(SEQ / 64, NHEADS);
    attn_mfma<<<g2, 256, 0, stream>>>(q, k, v, att);

    dim3 g3(DMODEL / BN, SEQ / BM);
    gemm_kernel<1><<<g3, 256, 0, stream>>>(att, wout_b, nullptr, nullptr, nullptr, out, SEQ, DMODEL, DINNER);
}

// Round 7
// 154.466 us; speedup vs baseline: 2.1856x; 1.2608x over previous
//
#include <hip/hip_runtime.h>
#include <hip/hip_bf16.h>
#include <math.h>

// Problem constants (B=1)
#define SEQ    4096
#define DMODEL 1024
#define NHEADS 8
#define DH     64
#define DINNER 512      // NHEADS*DH
#define NQKV   1536     // 3*DINNER
#define WINDOW 128
#define PERSIST 4
#define EPS 1.1920929e-07f

typedef unsigned short u16;
typedef unsigned int   u32;
typedef __bf16  bf16_8 __attribute__((ext_vector_type(8)));
typedef float   f32x4  __attribute__((ext_vector_type(4)));

union BV { bf16_8 v; u16 s[8]; };

__device__ __forceinline__ float b2f(u16 u) {
    union { u32 i; float f; } v; v.i = ((u32)u) << 16; return v.f;
}
__device__ __forceinline__ u16 f2b(float f) {
    union { float f; u32 i; } v; v.f = f;
    u32 i = v.i;
    u32 r = (i + 0x7fffu + ((i >> 16) & 1u)) >> 16;   // round-to-nearest-even
    return (u16)r;
}

// async 16B global->LDS (lane i of the wave lands at ldsbase + i*16)
#define GLD16(gp, lp) __builtin_amdgcn_global_load_lds( \
    (const __attribute__((address_space(1))) void*)(gp), \
    (__attribute__((address_space(3))) void*)(lp), 16, 0, 0)

// ---------------- weight transpose + fp32->bf16: dst[N][K] = src[K][N]^T ----------------
__global__ __launch_bounds__(256) void transpose_kernel(const float* __restrict__ src,
                                                        u16* __restrict__ dst,
                                                        int K, int N) {
    __shared__ u16 t[64][65];
    int bn = blockIdx.x * 64, bk = blockIdx.y * 64;
    int tid = threadIdx.x;
    int r = tid >> 4, c4 = (tid & 15) * 4;
    #pragma unroll
    for (int it = 0; it < 4; it++) {
        int row = r + it * 16;
        float4 v = *(const float4*)(src + (size_t)(bk + row) * N + bn + c4);
        t[row][c4 + 0] = f2b(v.x);
        t[row][c4 + 1] = f2b(v.y);
        t[row][c4 + 2] = f2b(v.z);
        t[row][c4 + 3] = f2b(v.w);
    }
    __syncthreads();
    #pragma unroll
    for (int it = 0; it < 4; it++) {
        int n = r + it * 16;
        u16* d = dst + (size_t)(bn + n) * K + bk + c4;
        d[0] = t[c4 + 0][n];
        d[1] = t[c4 + 1][n];
        d[2] = t[c4 + 2][n];
        d[3] = t[c4 + 3][n];
    }
}

// ---------------- RMSNorm (fp32 in, bf16 out) ----------------
__global__ __launch_bounds__(256) void rmsnorm_kernel(const float* __restrict__ seq,
                                                      const float* __restrict__ g,
                                                      u16* __restrict__ x) {
    int row = blockIdx.x, tid = threadIdx.x;          // 256 threads, 4 elems each
    float4 v = *(const float4*)(seq + (size_t)row * DMODEL + tid * 4);
    float ss = v.x*v.x + v.y*v.y + v.z*v.z + v.w*v.w;
    #pragma unroll
    for (int o = 32; o > 0; o >>= 1) ss += __shfl_xor(ss, o);
    __shared__ float wsum[4];
    if ((tid & 63) == 0) wsum[tid >> 6] = ss;
    __syncthreads();
    float tot = wsum[0] + wsum[1] + wsum[2] + wsum[3];
    float rstd = rsqrtf(tot * (1.0f / DMODEL) + EPS);
    float4 gv = *(const float4*)(g + tid * 4);
    uint2 o;
    o.x = (u32)f2b(v.x * rstd * gv.x) | ((u32)f2b(v.y * rstd * gv.y) << 16);
    o.y = (u32)f2b(v.z * rstd * gv.z) | ((u32)f2b(v.w * rstd * gv.w) << 16);
    *(uint2*)(x + (size_t)row * DMODEL + tid * 4) = o;
}

// ---------------- 128x128 MFMA GEMM, global_load_lds staging ----------------
// C[M,N] = A[M,K] @ Bt[N,K]^T  (both operands k-contiguous, bf16)
// LDS layout (A and B identical): elem(row, kc) at group g=row>>3, byte
// g*1024 + kc*128 + (row&7)*16  -> ds_read_b128 of 16 rows @ fixed kc hits
// each bank pair exactly twice (2-way = free).
// MODE 0: scatter bf16 C into q/k/v [head][n][64].  MODE 1: fp32 row-major.
template <int MODE>
__global__ __launch_bounds__(256, 2) void gemm2_kernel(const u16* __restrict__ A,
                                                       const u16* __restrict__ Bt,
                                                       u16* __restrict__ C0,
                                                       u16* __restrict__ C1,
                                                       u16* __restrict__ C2,
                                                       float* __restrict__ Cf,
                                                       int M, int N, int K) {
    __shared__ u16 As[128 * 64];   // 16 KB
    __shared__ u16 Bs[128 * 64];   // 16 KB
    int bx = blockIdx.x, by = blockIdx.y, tid = threadIdx.x;
    int lane = tid & 63, wave = tid >> 6;
    int m16 = lane & 15, quad = lane >> 4;
    int rw0 = (wave & 1) * 64, cw0 = (wave >> 1) * 64;

    f32x4 acc[4][4];
    #pragma unroll
    for (int mt = 0; mt < 4; mt++)
        #pragma unroll
        for (int nt = 0; nt < 4; nt++) acc[mt][nt] = (f32x4){0.f, 0.f, 0.f, 0.f};

    int lrow = lane & 7, lkc = lane >> 3;             // staging: 8 rows x 8 kchunks / wave-load
    const u16* Ag = A  + (size_t)(by * 128 + lrow) * K + lkc * 8;
    const u16* Bg = Bt + (size_t)(bx * 128 + lrow) * K + lkc * 8;

    for (int k0 = 0; k0 < K; k0 += 64) {
        #pragma unroll
        for (int r = 0; r < 4; r++) {
            int g = wave * 4 + r;                     // row-group 0..15
            GLD16(Ag + (size_t)(g * 8) * K + k0, As + g * 512);
            GLD16(Bg + (size_t)(g * 8) * K + k0, Bs + g * 512);
        }
        __syncthreads();

        #pragma unroll
        for (int kk = 0; kk < 2; kk++) {
            int kc = kk * 4 + quad;
            bf16_8 afr[4], bfr[4];
            #pragma unroll
            for (int mt = 0; mt < 4; mt++) {
                int row = rw0 + mt * 16 + m16;
                afr[mt] = *(const bf16_8*)(As + (row >> 3) * 512 + kc * 64 + (row & 7) * 8);
            }
            #pragma unroll
            for (int nt = 0; nt < 4; nt++) {
                int col = cw0 + nt * 16 + m16;
                bfr[nt] = *(const bf16_8*)(Bs + (col >> 3) * 512 + kc * 64 + (col & 7) * 8);
            }
            #pragma unroll
            for (int mt = 0; mt < 4; mt++)
                #pragma unroll
                for (int nt = 0; nt < 4; nt++)
                    acc[mt][nt] = __builtin_amdgcn_mfma_f32_16x16x32_bf16(afr[mt], bfr[nt], acc[mt][nt], 0, 0, 0);
        }
        __syncthreads();
    }

    // epilogue: C/D layout row=quad*4+r, col=lane&15
    #pragma unroll
    for (int mt = 0; mt < 4; mt++) {
        #pragma unroll
        for (int nt = 0; nt < 4; nt++) {
            #pragma unroll
            for (int r = 0; r < 4; r++) {
                int row = by * 128 + rw0 + mt * 16 + quad * 4 + r;
                int col = bx * 128 + cw0 + nt * 16 + m16;
                if (MODE == 0) {
                    int tens = col >> 9, hh = (col >> 6) & 7, dh = col & 63;
                    u16* dst = (tens == 0) ? C0 : ((tens == 1) ? C1 : C2);
                    dst[((size_t)hh * SEQ + row) * DH + dh] = f2b(acc[mt][nt][r]);
                } else {
                    Cf[(size_t)row * N + col] = acc[mt][nt][r];
                }
            }
        }
    }
}

// ---------------- RoPE (interleaved pairs), in place on q and k ----------------
__global__ __launch_bounds__(256) void rope_kernel(u16* __restrict__ Q, u16* __restrict__ Kt) {
    int idx = blockIdx.x * 256 + threadIdx.x;        // 2 * 2^20 threads
    int tensor = idx >> 20;
    int r = idx & 0xfffff;
    int t = r & 31;                                   // pair index 0..31
    int n = (r >> 5) & 4095;
    int h = r >> 17;
    u16* p = (tensor == 0 ? Q : Kt) + ((size_t)h * SEQ + n) * DH + 2 * t;
    float e = (float)(2 * t) / 64.0f;
    float inv = exp2f(-e * 13.287712379549449f);      // 10000^-e
    float ang = (float)n * inv;
    float s, c;
    sincosf(ang, &s, &c);
    float x0 = b2f(p[0]), x1 = b2f(p[1]);
    p[0] = f2b(x0 * c - x1 * s);
    p[1] = f2b(x1 * c + x0 * s);
}

// ---------------- Attention: MFMA flash-style (unchanged from round 6) ----------------
#define AROWS 208
#define KLD   72
#define PLD   168

__global__ __launch_bounds__(256, 2) void attn_mfma(const u16* __restrict__ Q,
                                                    const u16* __restrict__ Kt,
                                                    const u16* __restrict__ V,
                                                    u16* __restrict__ O) {
    __shared__ u16 Ks[AROWS * KLD];
    __shared__ u16 Vs[AROWS * 64];
    __shared__ u16 Ps[4 * 16 * PLD];
    int i0 = blockIdx.x * 64, h = blockIdx.y;
    int tid = threadIdx.x, wave = tid >> 6, lane = tid & 63;
    int m16 = lane & 15, quad = lane >> 4;
    int smin = (i0 > WINDOW) ? i0 - WINDOW : 0;

    for (int idx = tid; idx < AROWS * 8; idx += 256) {
        int row = idx >> 3, c = idx & 7;
        int j = (row < 16) ? row : (smin + row - 16);
        size_t goff = ((size_t)h * SEQ + j) * DH + c * 8;
        *(bf16_8*)(Ks + row * KLD + c * 8) = *(const bf16_8*)(Kt + goff);
        int swz = (row ^ (row >> 3)) & 7;
        *(bf16_8*)(Vs + row * 64 + ((c ^ swz) << 3)) = *(const bf16_8*)(V + goff);
    }

    int iw0 = i0 + wave * 16;
    int iq = iw0 + m16;
    const u16* qrow = Q + ((size_t)h * SEQ + iq) * DH;
    bf16_8 qa = *(const bf16_8*)(qrow + quad * 8);
    bf16_8 qb = *(const bf16_8*)(qrow + 32 + quad * 8);
    __syncthreads();

    int start_w = (iw0 > WINDOW) ? iw0 - WINDOW : 0;
    int Dw = start_w - smin;
    int tlast = 31 + iw0 - start_w;
    int nch = (tlast >> 4) + 1;
    int nk32 = (tlast >> 5) + 1;

    f32x4 S[10];
    #pragma unroll
    for (int c = 0; c < 10; c++) {
        if (c < nch) {
            int t = c * 16 + m16;
            int row = (c == 0) ? t : (t + Dw);
            const u16* kp = Ks + row * KLD;
            bf16_8 kb0 = *(const bf16_8*)(kp + quad * 8);
            bf16_8 kb1 = *(const bf16_8*)(kp + 32 + quad * 8);
            f32x4 s = (f32x4){0.f, 0.f, 0.f, 0.f};
            s = __builtin_amdgcn_mfma_f32_16x16x32_bf16(qa, kb0, s, 0, 0, 0);
            s = __builtin_amdgcn_mfma_f32_16x16x32_bf16(qb, kb1, s, 0, 0, 0);
            S[c] = s;
        }
    }

    float mrow[4] = {-1e30f, -1e30f, -1e30f, -1e30f};
    #pragma unroll
    for (int c = 0; c < 10; c++) {
        if (c < nch) {
            int t = c * 16 + m16;
            int j = (c == 0) ? t : (start_w + t - 16);
            #pragma unroll
            for (int r = 0; r < 4; r++) {
                int i = iw0 + quad * 4 + r;
                bool valid = (c == 0) ? (j < PERSIST && j < start_w)
                                      : (j <= i && (i - j <= WINDOW || j < PERSIST));
                float sv = valid ? S[c][r] * 0.125f : -1e30f;
                S[c][r] = sv;
                mrow[r] = fmaxf(mrow[r], sv);
            }
        }
    }
    #pragma unroll
    for (int r = 0; r < 4; r++) {
        #pragma unroll
        for (int o = 1; o < 16; o <<= 1) mrow[r] = fmaxf(mrow[r], __shfl_xor(mrow[r], o));
    }
    float srow[4] = {0.f, 0.f, 0.f, 0.f};
    #pragma unroll
    for (int c = 0; c < 10; c++) {
        if (c < nch) {
            #pragma unroll
            for (int r = 0; r < 4; r++) {
                float p = expf(S[c][r] - mrow[r]);
                S[c][r] = p;
                srow[r] += p;
            }
        }
    }
    #pragma unroll
    for (int r = 0; r < 4; r++) {
        #pragma unroll
        for (int o = 1; o < 16; o <<= 1) srow[r] += __shfl_xor(srow[r], o);
    }

    u16* pw = Ps + wave * 16 * PLD;
    #pragma unroll
    for (int c = 0; c < 10; c++) {
        #pragma unroll
        for (int r = 0; r < 4; r++) {
            u16 val = (c < nch) ? f2b(S[c][r]) : (u16)0;
            pw[(quad * 4 + r) * PLD + c * 16 + m16] = val;
        }
    }

    f32x4 oacc[4];
    #pragma unroll
    for (int nt = 0; nt < 4; nt++) oacc[nt] = (f32x4){0.f, 0.f, 0.f, 0.f};
    #pragma unroll
    for (int c2 = 0; c2 < 5; c2++) {
        if (c2 < nk32) {
            bf16_8 af = *(const bf16_8*)(pw + m16 * PLD + c2 * 32 + quad * 8);
            #pragma unroll
            for (int nt = 0; nt < 4; nt++) {
                union BV bv;
                int d = nt * 16 + m16;
                #pragma unroll
                for (int jj = 0; jj < 8; jj++) {
                    int k = c2 * 32 + quad * 8 + jj;
                    int row = (k < 16) ? k : (k + Dw);
                    int swz = (row ^ (row >> 3)) & 7;
                    bv.s[jj] = Vs[row * 64 + ((((d >> 3) ^ swz) << 3) | (d & 7))];
                }
                oacc[nt] = __builtin_amdgcn_mfma_f32_16x16x32_bf16(af, bv.v, oacc[nt], 0, 0, 0);
            }
        }
    }

    #pragma unroll
    for (int nt = 0; nt < 4; nt++) {
        #pragma unroll
        for (int r = 0; r < 4; r++) {
            int i = iw0 + quad * 4 + r;
            O[(size_t)i * DINNER + h * DH + nt * 16 + m16] = f2b(oacc[nt][r] / srow[r]);
        }
    }
}

// ---------------- launch ----------------
extern "C" void kernel_launch(void* const* d_in, const int* in_sizes, int n_in,
                              void* d_out, int out_size, void* d_ws, size_t ws_size,
                              hipStream_t stream) {
    const float* seq  = (const float*)d_in[0];   // fp32 inputs
    const float* g    = (const float*)d_in[1];
    const float* wqkv = (const float*)d_in[2];
    const float* wout = (const float*)d_in[3];
    float* out = (float*)d_out;                   // fp32 output

    char* ws = (char*)d_ws;
    u16* x       = (u16*)(ws);                            // 8 MB
    u16* q       = (u16*)(ws + 8ll  * 1024 * 1024);       // 4 MB
    u16* k       = (u16*)(ws + 12ll * 1024 * 1024);       // 4 MB
    u16* v       = (u16*)(ws + 16ll * 1024 * 1024);       // 4 MB
    u16* att     = (u16*)(ws + 20ll * 1024 * 1024);       // 4 MB
    u16* wqkv_bt = (u16*)(ws + 24ll * 1024 * 1024);       // [1536][1024] bf16, 3 MB
    u16* wout_bt = (u16*)(ws + 27ll * 1024 * 1024);       // [1024][512]  bf16, 1 MB

    // transposed bf16 weights: wqkv_bt[n][k], wout_bt[n][k]
    dim3 t1(NQKV / 64, DMODEL / 64);
    transpose_kernel<<<t1, 256, 0, stream>>>(wqkv, wqkv_bt, DMODEL, NQKV);
    dim3 t2(DMODEL / 64, DINNER / 64);
    transpose_kernel<<<t2, 256, 0, stream>>>(wout, wout_bt, DINNER, DMODEL);

    rmsnorm_kernel<<<SEQ, 256, 0, stream>>>(seq, g, x);

    dim3 g1(NQKV / 128, SEQ / 128);
    gemm2_kernel<0><<<g1, 256, 0, stream>>>(x, wqkv_bt, q, k, v, nullptr, SEQ, NQKV, DMODEL);

    rope_kernel<<<(2 * 1048576) / 256, 256, 0, stream>>>(q, k);

    dim3 g2(SEQ / 64, NHEADS);
    attn_mfma<<<g2, 256, 0, stream>>>(q, k, v, att);

    dim3 g3(DMODEL / 128, SEQ / 128);
    gemm2_kernel<1><<<g3, 256, 0, stream>>>(att, wout_bt, nullptr, nullptr, nullptr, out, SEQ, DMODEL, DINNER);
}

// Round 8
// 146.819 us; speedup vs baseline: 2.2994x; 1.0521x over previous
//
#include <hip/hip_runtime.h>
#include <hip/hip_bf16.h>
#include <math.h>

// Problem constants (B=1)
#define SEQ    4096
#define DMODEL 1024
#define NHEADS 8
#define DH     64
#define DINNER 512      // NHEADS*DH
#define NQKV   1536     // 3*DINNER
#define WINDOW 128
#define PERSIST 4
#define EPS 1.1920929e-07f

typedef unsigned short u16;
typedef unsigned int   u32;
typedef __bf16  bf16_8 __attribute__((ext_vector_type(8)));
typedef float   f32x4  __attribute__((ext_vector_type(4)));

union BV { bf16_8 v; u16 s[8]; };

__device__ __forceinline__ float b2f(u16 u) {
    union { u32 i; float f; } v; v.i = ((u32)u) << 16; return v.f;
}
__device__ __forceinline__ u16 f2b(float f) {
    union { float f; u32 i; } v; v.f = f;
    u32 i = v.i;
    u32 r = (i + 0x7fffu + ((i >> 16) & 1u)) >> 16;   // round-to-nearest-even
    return (u16)r;
}

// async 16B global->LDS (lane i of the wave lands at ldsbase + i*16)
#define GLD16(gp, lp) __builtin_amdgcn_global_load_lds( \
    (const __attribute__((address_space(1))) void*)(gp), \
    (__attribute__((address_space(3))) void*)(lp), 16, 0, 0)

// ---------------- prep: weight transposes (fp32->bf16) + RMSNorm, one dispatch ----------------
// blocks 0..383: wqkv tile; 384..511: wout tile; 512..4607: rmsnorm row.
__device__ __forceinline__ void transpose_tile(const float* __restrict__ src,
                                               u16* __restrict__ dst,
                                               int K, int N, int bn, int bk,
                                               u16 (*t)[65], int tid) {
    int r = tid >> 4, c4 = (tid & 15) * 4;
    #pragma unroll
    for (int it = 0; it < 4; it++) {
        int row = r + it * 16;
        float4 v = *(const float4*)(src + (size_t)(bk + row) * N + bn + c4);
        t[row][c4 + 0] = f2b(v.x);
        t[row][c4 + 1] = f2b(v.y);
        t[row][c4 + 2] = f2b(v.z);
        t[row][c4 + 3] = f2b(v.w);
    }
    __syncthreads();
    #pragma unroll
    for (int it = 0; it < 4; it++) {
        int n = r + it * 16;
        u16* d = dst + (size_t)(bn + n) * K + bk + c4;
        d[0] = t[c4 + 0][n];
        d[1] = t[c4 + 1][n];
        d[2] = t[c4 + 2][n];
        d[3] = t[c4 + 3][n];
    }
}

__global__ __launch_bounds__(256) void prep_kernel(const float* __restrict__ wqkv,
                                                   const float* __restrict__ wout,
                                                   const float* __restrict__ seq,
                                                   const float* __restrict__ g,
                                                   u16* __restrict__ wqkv_bt,
                                                   u16* __restrict__ wout_bt,
                                                   u16* __restrict__ x) {
    __shared__ u16 t[64][65];
    __shared__ float wsum[4];
    int b = blockIdx.x, tid = threadIdx.x;
    if (b < 384) {
        transpose_tile(wqkv, wqkv_bt, DMODEL, NQKV, (b % 24) * 64, (b / 24) * 64, t, tid);
    } else if (b < 512) {
        int bb = b - 384;
        transpose_tile(wout, wout_bt, DINNER, DMODEL, (bb % 16) * 64, (bb / 16) * 64, t, tid);
    } else {
        int row = b - 512;
        float4 v = *(const float4*)(seq + (size_t)row * DMODEL + tid * 4);
        float ss = v.x*v.x + v.y*v.y + v.z*v.z + v.w*v.w;
        #pragma unroll
        for (int o = 32; o > 0; o >>= 1) ss += __shfl_xor(ss, o);
        if ((tid & 63) == 0) wsum[tid >> 6] = ss;
        __syncthreads();
        float tot = wsum[0] + wsum[1] + wsum[2] + wsum[3];
        float rstd = rsqrtf(tot * (1.0f / DMODEL) + EPS);
        float4 gv = *(const float4*)(g + tid * 4);
        uint2 o;
        o.x = (u32)f2b(v.x * rstd * gv.x) | ((u32)f2b(v.y * rstd * gv.y) << 16);
        o.y = (u32)f2b(v.z * rstd * gv.z) | ((u32)f2b(v.w * rstd * gv.w) << 16);
        *(uint2*)(x + (size_t)row * DMODEL + tid * 4) = o;
    }
}

// ---------------- 128x128 MFMA GEMM, global_load_lds staging ----------------
// C[M,N] = A[M,K] @ Bt[N,K]^T  (both operands k-contiguous, bf16)
// MODE 0: scatter bf16 C into q/k/v [head][n][64] with FUSED RoPE on q,k.
// MODE 1: fp32 row-major write.
template <int MODE>
__global__ __launch_bounds__(256, 2) void gemm2_kernel(const u16* __restrict__ A,
                                                       const u16* __restrict__ Bt,
                                                       u16* __restrict__ C0,
                                                       u16* __restrict__ C1,
                                                       u16* __restrict__ C2,
                                                       float* __restrict__ Cf,
                                                       int M, int N, int K) {
    __shared__ u16 As[128 * 64];   // 16 KB
    __shared__ u16 Bs[128 * 64];   // 16 KB
    int bx = blockIdx.x, by = blockIdx.y, tid = threadIdx.x;
    int lane = tid & 63, wave = tid >> 6;
    int m16 = lane & 15, quad = lane >> 4;
    int rw0 = (wave & 1) * 64, cw0 = (wave >> 1) * 64;

    f32x4 acc[4][4];
    #pragma unroll
    for (int mt = 0; mt < 4; mt++)
        #pragma unroll
        for (int nt = 0; nt < 4; nt++) acc[mt][nt] = (f32x4){0.f, 0.f, 0.f, 0.f};

    int lrow = lane & 7, lkc = lane >> 3;
    const u16* Ag = A  + (size_t)(by * 128 + lrow) * K + lkc * 8;
    const u16* Bg = Bt + (size_t)(bx * 128 + lrow) * K + lkc * 8;

    for (int k0 = 0; k0 < K; k0 += 64) {
        #pragma unroll
        for (int r = 0; r < 4; r++) {
            int gg = wave * 4 + r;
            GLD16(Ag + (size_t)(gg * 8) * K + k0, As + gg * 512);
            GLD16(Bg + (size_t)(gg * 8) * K + k0, Bs + gg * 512);
        }
        __syncthreads();

        #pragma unroll
        for (int kk = 0; kk < 2; kk++) {
            int kc = kk * 4 + quad;
            bf16_8 afr[4], bfr[4];
            #pragma unroll
            for (int mt = 0; mt < 4; mt++) {
                int row = rw0 + mt * 16 + m16;
                afr[mt] = *(const bf16_8*)(As + (row >> 3) * 512 + kc * 64 + (row & 7) * 8);
            }
            #pragma unroll
            for (int nt = 0; nt < 4; nt++) {
                int col = cw0 + nt * 16 + m16;
                bfr[nt] = *(const bf16_8*)(Bs + (col >> 3) * 512 + kc * 64 + (col & 7) * 8);
            }
            #pragma unroll
            for (int mt = 0; mt < 4; mt++)
                #pragma unroll
                for (int nt = 0; nt < 4; nt++)
                    acc[mt][nt] = __builtin_amdgcn_mfma_f32_16x16x32_bf16(afr[mt], bfr[nt], acc[mt][nt], 0, 0, 0);
        }
        __syncthreads();
    }

    // epilogue: C/D layout row=quad*4+r, col=lane&15
    #pragma unroll
    for (int nt = 0; nt < 4; nt++) {
        int col = bx * 128 + cw0 + nt * 16 + m16;
        if (MODE == 0) {
            // rope params (fixed per lane per nt): pair index t = (col&63)>>1
            int tt = (col & 63) >> 1;
            float inv = exp2f(-(float)(2 * tt) * (13.287712379549449f / 64.0f));
            bool isv = (col >= 2 * DINNER);
            bool odd = (col & 1);
            int tens = col >> 9, hh = (col >> 6) & 7, dh = col & 63;
            u16* dst = (tens == 0) ? C0 : ((tens == 1) ? C1 : C2);
            #pragma unroll
            for (int mt = 0; mt < 4; mt++) {
                #pragma unroll
                for (int r = 0; r < 4; r++) {
                    int row = by * 128 + rw0 + mt * 16 + quad * 4 + r;
                    float own = acc[mt][nt][r];
                    float part = __shfl_xor(own, 1);
                    float val = own;
                    if (!isv) {
                        float s, c;
                        __sincosf((float)row * inv, &s, &c);
                        val = odd ? (own * c + part * s) : (own * c - part * s);
                    }
                    dst[((size_t)hh * SEQ + row) * DH + dh] = f2b(val);
                }
            }
        } else {
            #pragma unroll
            for (int mt = 0; mt < 4; mt++) {
                #pragma unroll
                for (int r = 0; r < 4; r++) {
                    int row = by * 128 + rw0 + mt * 16 + quad * 4 + r;
                    Cf[(size_t)row * N + col] = acc[mt][nt][r];
                }
            }
        }
    }
}

// ---------------- Attention: MFMA flash-style, Vt layout for b128 PV reads ----------------
#define AROWS 208
#define KLD   72      // Ks row stride (u16)
#define PLD   168     // Ps row stride (u16)
#define VLD   222     // Vt row stride (u16): 444B spreads banks (~4-way worst)

__global__ __launch_bounds__(256, 2) void attn_mfma(const u16* __restrict__ Q,
                                                    const u16* __restrict__ Kt,
                                                    const u16* __restrict__ V,
                                                    u16* __restrict__ O) {
    // Ps aliases Ks (dead after QK); Vt separate. 29952 + 64*222*2 = 58368 B.
    __shared__ __align__(16) char smem[29952 + 64 * VLD * 2];
    u16* Ks = (u16*)smem;                       // [208][72]
    u16* Ps = (u16*)smem;                       // [4*16][168]  (after barrier)
    u16* Vt = (u16*)(smem + 29952);             // [64][222]    d-major
    int i0 = blockIdx.x * 64, h = blockIdx.y;
    int tid = threadIdx.x, wave = tid >> 6, lane = tid & 63;
    int m16 = lane & 15, quad = lane >> 4;
    int smin = (i0 > WINDOW) ? i0 - WINDOW : 0;

    for (int idx = tid; idx < AROWS * 8; idx += 256) {
        int row = idx >> 3, c = idx & 7;
        int j = (row < 16) ? row : (smin + row - 16);
        size_t goff = ((size_t)h * SEQ + j) * DH + c * 8;
        *(bf16_8*)(Ks + row * KLD + c * 8) = *(const bf16_8*)(Kt + goff);
        union BV u; u.v = *(const bf16_8*)(V + goff);
        #pragma unroll
        for (int e = 0; e < 8; e++) Vt[(c * 8 + e) * VLD + row] = u.s[e];
    }

    int iw0 = i0 + wave * 16;
    int iq = iw0 + m16;
    const u16* qrow = Q + ((size_t)h * SEQ + iq) * DH;
    bf16_8 qa = *(const bf16_8*)(qrow + quad * 8);
    bf16_8 qb = *(const bf16_8*)(qrow + 32 + quad * 8);
    __syncthreads();

    int start_w = (iw0 > WINDOW) ? iw0 - WINDOW : 0;
    int Dw = start_w - smin;
    int tlast = 31 + iw0 - start_w;
    int nch = (tlast >> 4) + 1;                  // <=10
    int nk32 = (tlast >> 5) + 1;                 // <=5

    // ---- QK^T (reads Ks) ----
    f32x4 S[10];
    #pragma unroll
    for (int c = 0; c < 10; c++) {
        if (c < nch) {
            int t = c * 16 + m16;
            int row = (c == 0) ? t : (t + Dw);
            const u16* kp = Ks + row * KLD;
            bf16_8 kb0 = *(const bf16_8*)(kp + quad * 8);
            bf16_8 kb1 = *(const bf16_8*)(kp + 32 + quad * 8);
            f32x4 s = (f32x4){0.f, 0.f, 0.f, 0.f};
            s = __builtin_amdgcn_mfma_f32_16x16x32_bf16(qa, kb0, s, 0, 0, 0);
            s = __builtin_amdgcn_mfma_f32_16x16x32_bf16(qb, kb1, s, 0, 0, 0);
            S[c] = s;
        }
    }
    __syncthreads();   // Ks dead after this point; Ps may now overwrite it

    // ---- mask + softmax (registers only) ----
    float mrow[4] = {-1e30f, -1e30f, -1e30f, -1e30f};
    #pragma unroll
    for (int c = 0; c < 10; c++) {
        if (c < nch) {
            int t = c * 16 + m16;
            int j = (c == 0) ? t : (start_w + t - 16);
            #pragma unroll
            for (int r = 0; r < 4; r++) {
                int i = iw0 + quad * 4 + r;
                bool valid = (c == 0) ? (j < PERSIST && j < start_w)
                                      : (j <= i && (i - j <= WINDOW || j < PERSIST));
                float sv = valid ? S[c][r] * 0.125f : -1e30f;
                S[c][r] = sv;
                mrow[r] = fmaxf(mrow[r], sv);
            }
        }
    }
    #pragma unroll
    for (int r = 0; r < 4; r++) {
        #pragma unroll
        for (int o = 1; o < 16; o <<= 1) mrow[r] = fmaxf(mrow[r], __shfl_xor(mrow[r], o));
    }
    float srow[4] = {0.f, 0.f, 0.f, 0.f};
    #pragma unroll
    for (int c = 0; c < 10; c++) {
        if (c < nch) {
            #pragma unroll
            for (int r = 0; r < 4; r++) {
                float p = expf(S[c][r] - mrow[r]);
                S[c][r] = p;
                srow[r] += p;
            }
        }
    }
    #pragma unroll
    for (int r = 0; r < 4; r++) {
        #pragma unroll
        for (int o = 1; o < 16; o <<= 1) srow[r] += __shfl_xor(srow[r], o);
    }

    // ---- P -> LDS (C layout -> A layout); zero-fill unused ----
    u16* pw = Ps + wave * 16 * PLD;
    #pragma unroll
    for (int c = 0; c < 10; c++) {
        #pragma unroll
        for (int r = 0; r < 4; r++) {
            u16 val = (c < nch) ? f2b(S[c][r]) : (u16)0;
            pw[(quad * 4 + r) * PLD + c * 16 + m16] = val;
        }
    }

    // ---- PV: A from Ps (b128), B from Vt (b128) ----
    f32x4 oacc[4];
    #pragma unroll
    for (int nt = 0; nt < 4; nt++) oacc[nt] = (f32x4){0.f, 0.f, 0.f, 0.f};
    #pragma unroll
    for (int c2 = 0; c2 < 5; c2++) {
        if (c2 < nk32) {
            bf16_8 af = *(const bf16_8*)(pw + m16 * PLD + c2 * 32 + quad * 8);
            int kbase = c2 * 32 + quad * 8;
            int rowb = (kbase < 16) ? kbase : (kbase + Dw);
            #pragma unroll
            for (int nt = 0; nt < 4; nt++) {
                int d = nt * 16 + m16;
                bf16_8 bv = *(const bf16_8*)(Vt + d * VLD + rowb);
                oacc[nt] = __builtin_amdgcn_mfma_f32_16x16x32_bf16(af, bv, oacc[nt], 0, 0, 0);
            }
        }
    }

    #pragma unroll
    for (int nt = 0; nt < 4; nt++) {
        #pragma unroll
        for (int r = 0; r < 4; r++) {
            int i = iw0 + quad * 4 + r;
            O[(size_t)i * DINNER + h * DH + nt * 16 + m16] = f2b(oacc[nt][r] / srow[r]);
        }
    }
}

// ---------------- launch ----------------
extern "C" void kernel_launch(void* const* d_in, const int* in_sizes, int n_in,
                              void* d_out, int out_size, void* d_ws, size_t ws_size,
                              hipStream_t stream) {
    const float* seq  = (const float*)d_in[0];   // fp32 inputs
    const float* g    = (const float*)d_in[1];
    const float* wqkv = (const float*)d_in[2];
    const float* wout = (const float*)d_in[3];
    float* out = (float*)d_out;                   // fp32 output

    char* ws = (char*)d_ws;
    u16* x       = (u16*)(ws);                            // 8 MB
    u16* q       = (u16*)(ws + 8ll  * 1024 * 1024);       // 4 MB
    u16* k       = (u16*)(ws + 12ll * 1024 * 1024);       // 4 MB
    u16* v       = (u16*)(ws + 16ll * 1024 * 1024);       // 4 MB
    u16* att     = (u16*)(ws + 20ll * 1024 * 1024);       // 4 MB
    u16* wqkv_bt = (u16*)(ws + 24ll * 1024 * 1024);       // [1536][1024] bf16, 3 MB
    u16* wout_bt = (u16*)(ws + 27ll * 1024 * 1024);       // [1024][512]  bf16, 1 MB

    prep_kernel<<<4608, 256, 0, stream>>>(wqkv, wout, seq, g, wqkv_bt, wout_bt, x);

    dim3 g1(NQKV / 128, SEQ / 128);
    gemm2_kernel<0><<<g1, 256, 0, stream>>>(x, wqkv_bt, q, k, v, nullptr, SEQ, NQKV, DMODEL);

    dim3 g2(SEQ / 64, NHEADS);
    attn_mfma<<<g2, 256, 0, stream>>>(q, k, v, att);

    dim3 g3(DMODEL / 128, SEQ / 128);
    gemm2_kernel<1><<<g3, 256, 0, stream>>>(att, wout_bt, nullptr, nullptr, nullptr, out, SEQ, DMODEL, DINNER);
}